// Round 1
// baseline (676.051 us; speedup 1.0000x reference)
//
#include <hip/hip_runtime.h>

#define N_ROWS 131072
#define KCODES 1024
#define DIM 64
#define BLOCK 256

// h: [32, 64, 64, 64] fp32  (B, D, H, W) -> row n = b*4096 + y*64 + x reads h[b][d][y][x]
// codebook: [1024, 64] fp32
// out: [131072] z-as-float ++ [131072*64] q fp32

__global__ __launch_bounds__(BLOCK, 2) void vq_argmin_kernel(
    const float* __restrict__ h,
    const float* __restrict__ cb,
    float* __restrict__ z_out,
    float* __restrict__ q_out)
{
    __shared__ float s_c2[KCODES];
    __shared__ int   s_idx[BLOCK];

    const int tid = threadIdx.x;
    const int row = blockIdx.x * BLOCK + tid;

    // ---- c2[k] = ||codebook[k]||^2, numpy-pairwise order (8 strided accumulators) ----
    {
#pragma clang fp contract(off)
#pragma unroll
        for (int kk = 0; kk < KCODES / BLOCK; ++kk) {
            const int k = kk * BLOCK + tid;
            const float* c = cb + k * DIM;
            float r[8];
#pragma unroll
            for (int j = 0; j < 8; ++j) {
                float t = c[j];
                r[j] = t * t;
            }
#pragma unroll
            for (int i = 1; i < 8; ++i) {
#pragma unroll
                for (int j = 0; j < 8; ++j) {
                    float t = c[i * 8 + j];
                    float sq = t * t;      // rounded product first (no fma contraction)
                    r[j] = r[j] + sq;
                }
            }
            s_c2[k] = ((r[0] + r[1]) + (r[2] + r[3])) + ((r[4] + r[5]) + (r[6] + r[7]));
        }
    }
    __syncthreads();

    // ---- load this thread's row x[0..63]; stride 4096 floats across d, lanes coalesced ----
    const int b  = row >> 12;        // 4096 rows per batch image
    const int yx = row & 4095;
    const float* hp = h + (size_t)b * (DIM * 4096) + yx;

    float x[DIM];
#pragma unroll
    for (int d = 0; d < DIM; ++d) x[d] = hp[(size_t)d * 4096];

    // ---- S = ||x||^2, numpy pairwise order ----
    float S;
    {
#pragma clang fp contract(off)
        float r[8];
#pragma unroll
        for (int j = 0; j < 8; ++j) r[j] = x[j] * x[j];
#pragma unroll
        for (int i = 1; i < 8; ++i) {
#pragma unroll
            for (int j = 0; j < 8; ++j) {
                float sq = x[i * 8 + j] * x[i * 8 + j];
                r[j] = r[j] + sq;
            }
        }
        S = ((r[0] + r[1]) + (r[2] + r[3])) + ((r[4] + r[5]) + (r[6] + r[7]));
    }

    // ---- main loop: 2 codes per iteration (2 independent fma chains) ----
    float best_d = 3.4e38f;
    int   best_k = 0;

    for (int k = 0; k < KCODES; k += 2) {
        const float* c0 = cb + (k << 6);
        const float* c1 = c0 + DIM;
        float a0 = 0.0f, a1 = 0.0f;
#pragma unroll
        for (int d = 0; d < DIM; ++d) {
            a0 = __builtin_fmaf(x[d], c0[d], a0);   // sequential chain, BLAS order
            a1 = __builtin_fmaf(x[d], c1[d], a1);
        }
        float d2a, d2b;
        {
#pragma clang fp contract(off)
            float ta = 2.0f * a0;        // exact
            float tb = 2.0f * a1;
            float ua = S - ta;           // rounded at ~64 magnitude, like np
            float ub = S - tb;
            d2a = ua + s_c2[k];
            d2b = ub + s_c2[k + 1];
        }
        if (d2a < best_d) { best_d = d2a; best_k = k; }
        if (d2b < best_d) { best_d = d2b; best_k = k + 1; }
    }

    // ---- outputs ----
    z_out[row] = (float)best_k;
    s_idx[tid] = best_k;
    __syncthreads();

    // cooperative q gather: bit-exact copy of codebook rows, coalesced float4 stores
    const int lane16 = tid & 15;   // float4 slot within a row (16 * 4 floats = 64)
    const int rsub   = tid >> 4;   // 0..15
    const float4* cb4 = (const float4*)cb;
    float4* q4 = (float4*)q_out;
    const int row_base = blockIdx.x * BLOCK;
#pragma unroll
    for (int it = 0; it < 16; ++it) {
        const int rl  = it * 16 + rsub;          // local row 0..255
        const int idx = s_idx[rl];
        q4[(size_t)(row_base + rl) * 16 + lane16] = cb4[idx * 16 + lane16];
    }
}

extern "C" void kernel_launch(void* const* d_in, const int* in_sizes, int n_in,
                              void* d_out, int out_size, void* d_ws, size_t ws_size,
                              hipStream_t stream) {
    const float* h  = (const float*)d_in[0];
    const float* cb = (const float*)d_in[1];
    float* out = (float*)d_out;
    float* z_out = out;              // 131072 floats
    float* q_out = out + N_ROWS;     // 131072*64 floats

    vq_argmin_kernel<<<dim3(N_ROWS / BLOCK), dim3(BLOCK), 0, stream>>>(h, cb, z_out, q_out);
}

// Round 2
// 551.290 us; speedup vs baseline: 1.2263x; 1.2263x over previous
//
#include <hip/hip_runtime.h>

#define N_ROWS 131072
#define KCODES 1024
#define DIM 64
#define BLOCK 256

// h: [32, 64, 64, 64] fp32 (B, D, H, W) -> row n = b*4096 + y*64 + x reads h[b][d][y][x]
// codebook: [1024, 64] fp32
// out: [131072] z-as-float ++ [131072*64] q fp32

__global__ __launch_bounds__(BLOCK, 2) void vq_argmin_kernel(
    const float* __restrict__ h,
    const float* __restrict__ cb,
    float* __restrict__ z_out,
    float* __restrict__ q_out)
{
    __shared__ float s_c2[KCODES];
    __shared__ int   s_idx[BLOCK];

    const int tid = threadIdx.x;
    const int row = blockIdx.x * BLOCK + tid;

    // ---- c2[k] = ||codebook[k]||^2, numpy-pairwise order (8 strided accumulators) ----
    {
#pragma clang fp contract(off)
#pragma unroll
        for (int kk = 0; kk < KCODES / BLOCK; ++kk) {
            const int k = kk * BLOCK + tid;
            const float* c = cb + k * DIM;
            float r0 = c[0]*c[0], r1 = c[1]*c[1], r2 = c[2]*c[2], r3 = c[3]*c[3];
            float r4 = c[4]*c[4], r5 = c[5]*c[5], r6 = c[6]*c[6], r7 = c[7]*c[7];
#pragma unroll
            for (int i = 1; i < 8; ++i) {
                r0 = r0 + c[i*8+0]*c[i*8+0];
                r1 = r1 + c[i*8+1]*c[i*8+1];
                r2 = r2 + c[i*8+2]*c[i*8+2];
                r3 = r3 + c[i*8+3]*c[i*8+3];
                r4 = r4 + c[i*8+4]*c[i*8+4];
                r5 = r5 + c[i*8+5]*c[i*8+5];
                r6 = r6 + c[i*8+6]*c[i*8+6];
                r7 = r7 + c[i*8+7]*c[i*8+7];
            }
            s_c2[k] = ((r0 + r1) + (r2 + r3)) + ((r4 + r5) + (r6 + r7));
        }
    }
    __syncthreads();

    // ---- this thread's row, 16 NAMED float4 (no arrays -> guaranteed VGPRs) ----
    const int b  = row >> 12;
    const int yx = row & 4095;
    const float* hp = h + (size_t)b * (DIM * 4096) + yx;

#define LD(d) hp[(size_t)(d) * 4096]
#define XDECL(n) float4 x##n = make_float4(LD(4*(n)+0), LD(4*(n)+1), LD(4*(n)+2), LD(4*(n)+3));
    XDECL(0)  XDECL(1)  XDECL(2)  XDECL(3)
    XDECL(4)  XDECL(5)  XDECL(6)  XDECL(7)
    XDECL(8)  XDECL(9)  XDECL(10) XDECL(11)
    XDECL(12) XDECL(13) XDECL(14) XDECL(15)
#undef XDECL
#undef LD

    // ---- S = ||x||^2, numpy pairwise (8 accumulators over elems i*8+j) ----
    float S;
    {
#pragma clang fp contract(off)
        float r0 = x0.x*x0.x, r1 = x0.y*x0.y, r2 = x0.z*x0.z, r3 = x0.w*x0.w;
        float r4 = x1.x*x1.x, r5 = x1.y*x1.y, r6 = x1.z*x1.z, r7 = x1.w*x1.w;
#define SQACC(ve, vo) \
        r0 = r0 + ve.x*ve.x; r1 = r1 + ve.y*ve.y; r2 = r2 + ve.z*ve.z; r3 = r3 + ve.w*ve.w; \
        r4 = r4 + vo.x*vo.x; r5 = r5 + vo.y*vo.y; r6 = r6 + vo.z*vo.z; r7 = r7 + vo.w*vo.w;
        SQACC(x2,  x3)  SQACC(x4,  x5)  SQACC(x6,  x7)
        SQACC(x8,  x9)  SQACC(x10, x11) SQACC(x12, x13)
        SQACC(x14, x15)
#undef SQACC
        S = ((r0 + r1) + (r2 + r3)) + ((r4 + r5) + (r6 + r7));
    }

    // ---- main loop: 2 codes/iter, 2 independent sequential FMA chains ----
    float best_d = 3.4e38f;
    int   best_k = 0;

#define DOT4(v, base) \
        a0 = __builtin_fmaf(v.x, c0[(base)+0], a0); a1 = __builtin_fmaf(v.x, c1[(base)+0], a1); \
        a0 = __builtin_fmaf(v.y, c0[(base)+1], a0); a1 = __builtin_fmaf(v.y, c1[(base)+1], a1); \
        a0 = __builtin_fmaf(v.z, c0[(base)+2], a0); a1 = __builtin_fmaf(v.z, c1[(base)+2], a1); \
        a0 = __builtin_fmaf(v.w, c0[(base)+3], a0); a1 = __builtin_fmaf(v.w, c1[(base)+3], a1);

    for (int k = 0; k < KCODES; k += 2) {
        const float* c0 = cb + (k << 6);   // wave-uniform -> s_load
        const float* c1 = c0 + DIM;
        float a0 = 0.0f, a1 = 0.0f;
        DOT4(x0,  0)  DOT4(x1,  4)  DOT4(x2,  8)  DOT4(x3,  12)
        DOT4(x4,  16) DOT4(x5,  20) DOT4(x6,  24) DOT4(x7,  28)
        DOT4(x8,  32) DOT4(x9,  36) DOT4(x10, 40) DOT4(x11, 44)
        DOT4(x12, 48) DOT4(x13, 52) DOT4(x14, 56) DOT4(x15, 60)

        float d2a, d2b;
        {
#pragma clang fp contract(off)
            float ta = 2.0f * a0;     // exact
            float tb = 2.0f * a1;
            float ua = S - ta;        // rounded like np
            float ub = S - tb;
            d2a = ua + s_c2[k];
            d2b = ub + s_c2[k + 1];
        }
        if (d2a < best_d) { best_d = d2a; best_k = k; }
        if (d2b < best_d) { best_d = d2b; best_k = k + 1; }
    }
#undef DOT4

    // ---- outputs ----
    z_out[row] = (float)best_k;
    s_idx[tid] = best_k;
    __syncthreads();

    // cooperative q gather: bit-exact codebook rows, coalesced float4 stores
    const int lane16 = tid & 15;
    const int rsub   = tid >> 4;
    const float4* cb4 = (const float4*)cb;
    float4* q4 = (float4*)q_out;
    const int row_base = blockIdx.x * BLOCK;
#pragma unroll
    for (int it = 0; it < 16; ++it) {
        const int rl  = it * 16 + rsub;
        const int idx = s_idx[rl];
        q4[(size_t)(row_base + rl) * 16 + lane16] = cb4[idx * 16 + lane16];
    }
}

extern "C" void kernel_launch(void* const* d_in, const int* in_sizes, int n_in,
                              void* d_out, int out_size, void* d_ws, size_t ws_size,
                              hipStream_t stream) {
    const float* h  = (const float*)d_in[0];
    const float* cb = (const float*)d_in[1];
    float* out = (float*)d_out;
    float* z_out = out;              // 131072 floats
    float* q_out = out + N_ROWS;     // 131072*64 floats

    vq_argmin_kernel<<<dim3(N_ROWS / BLOCK), dim3(BLOCK), 0, stream>>>(h, cb, z_out, q_out);
}

// Round 3
// 549.635 us; speedup vs baseline: 1.2300x; 1.0030x over previous
//
#include <hip/hip_runtime.h>

#define N_ROWS 131072
#define KCODES 1024
#define DIM 64
#define BLOCK 256

// h: [32, 64, 64, 64] fp32 (B, D, H, W) -> row n = b*4096 + y*64 + x reads h[b][d][y][x]
// codebook: [1024, 64] fp32
// out: [131072] z-as-float ++ [131072*64] q fp32

__global__ __launch_bounds__(BLOCK, 2) void vq_argmin_kernel(
    const float* __restrict__ h,
    const float* __restrict__ cb,
    float* __restrict__ z_out,
    float* __restrict__ q_out)
{
    __shared__ float s_c2[KCODES];
    __shared__ int   s_idx[BLOCK];

    const int tid = threadIdx.x;
    const int row = blockIdx.x * BLOCK + tid;

    // ---- c2[k] = ||codebook[k]||^2, numpy-pairwise order (8 strided accumulators) ----
    {
#pragma clang fp contract(off)
#pragma unroll
        for (int kk = 0; kk < KCODES / BLOCK; ++kk) {
            const int k = kk * BLOCK + tid;
            const float* c = cb + k * DIM;
            float r0 = c[0]*c[0], r1 = c[1]*c[1], r2 = c[2]*c[2], r3 = c[3]*c[3];
            float r4 = c[4]*c[4], r5 = c[5]*c[5], r6 = c[6]*c[6], r7 = c[7]*c[7];
#pragma unroll
            for (int i = 1; i < 8; ++i) {
                r0 = r0 + c[i*8+0]*c[i*8+0];
                r1 = r1 + c[i*8+1]*c[i*8+1];
                r2 = r2 + c[i*8+2]*c[i*8+2];
                r3 = r3 + c[i*8+3]*c[i*8+3];
                r4 = r4 + c[i*8+4]*c[i*8+4];
                r5 = r5 + c[i*8+5]*c[i*8+5];
                r6 = r6 + c[i*8+6]*c[i*8+6];
                r7 = r7 + c[i*8+7]*c[i*8+7];
            }
            s_c2[k] = ((r0 + r1) + (r2 + r3)) + ((r4 + r5) + (r6 + r7));
        }
    }
    __syncthreads();

    // ---- this thread's row: 16 float4, PINNED to VGPRs via asm (non-rematerializable) ----
    const int b  = row >> 12;
    const int yx = row & 4095;
    const float* hp = h + (size_t)b * (DIM * 4096) + yx;

#define LD(d) hp[(size_t)(d) * 4096]
#define XDECL(n) float4 x##n = make_float4(LD(4*(n)+0), LD(4*(n)+1), LD(4*(n)+2), LD(4*(n)+3)); \
    asm("" : "+v"(x##n.x), "+v"(x##n.y), "+v"(x##n.z), "+v"(x##n.w));
    XDECL(0)  XDECL(1)  XDECL(2)  XDECL(3)
    XDECL(4)  XDECL(5)  XDECL(6)  XDECL(7)
    XDECL(8)  XDECL(9)  XDECL(10) XDECL(11)
    XDECL(12) XDECL(13) XDECL(14) XDECL(15)
#undef XDECL
#undef LD

    // ---- S = ||x||^2, numpy pairwise (8 accumulators over elems i*8+j) ----
    float S;
    {
#pragma clang fp contract(off)
        float r0 = x0.x*x0.x, r1 = x0.y*x0.y, r2 = x0.z*x0.z, r3 = x0.w*x0.w;
        float r4 = x1.x*x1.x, r5 = x1.y*x1.y, r6 = x1.z*x1.z, r7 = x1.w*x1.w;
#define SQACC(ve, vo) \
        r0 = r0 + ve.x*ve.x; r1 = r1 + ve.y*ve.y; r2 = r2 + ve.z*ve.z; r3 = r3 + ve.w*ve.w; \
        r4 = r4 + vo.x*vo.x; r5 = r5 + vo.y*vo.y; r6 = r6 + vo.z*vo.z; r7 = r7 + vo.w*vo.w;
        SQACC(x2,  x3)  SQACC(x4,  x5)  SQACC(x6,  x7)
        SQACC(x8,  x9)  SQACC(x10, x11) SQACC(x12, x13)
        SQACC(x14, x15)
#undef SQACC
        S = ((r0 + r1) + (r2 + r3)) + ((r4 + r5) + (r6 + r7));
    }

    // ---- main loop: 2 codes/iter, 2 independent sequential FMA chains ----
    float best_d = 3.4e38f;
    int   best_k = 0;

#define DOT4(v, base) \
        a0 = __builtin_fmaf(v.x, c0[(base)+0], a0); a1 = __builtin_fmaf(v.x, c1[(base)+0], a1); \
        a0 = __builtin_fmaf(v.y, c0[(base)+1], a0); a1 = __builtin_fmaf(v.y, c1[(base)+1], a1); \
        a0 = __builtin_fmaf(v.z, c0[(base)+2], a0); a1 = __builtin_fmaf(v.z, c1[(base)+2], a1); \
        a0 = __builtin_fmaf(v.w, c0[(base)+3], a0); a1 = __builtin_fmaf(v.w, c1[(base)+3], a1);

    for (int k = 0; k < KCODES; k += 2) {
        const float* c0 = cb + (k << 6);   // wave-uniform -> s_load stream
        const float* c1 = c0 + DIM;
        float a0 = 0.0f, a1 = 0.0f;
        DOT4(x0,  0)  DOT4(x1,  4)  DOT4(x2,  8)  DOT4(x3,  12)
        DOT4(x4,  16) DOT4(x5,  20) DOT4(x6,  24) DOT4(x7,  28)
        DOT4(x8,  32) DOT4(x9,  36) DOT4(x10, 40) DOT4(x11, 44)
        DOT4(x12, 48) DOT4(x13, 52) DOT4(x14, 56) DOT4(x15, 60)

        float d2a, d2b;
        {
#pragma clang fp contract(off)
            float ta = 2.0f * a0;     // exact
            float tb = 2.0f * a1;
            float ua = S - ta;        // rounded like np
            float ub = S - tb;
            d2a = ua + s_c2[k];
            d2b = ub + s_c2[k + 1];
        }
        if (d2a < best_d) { best_d = d2a; best_k = k; }
        if (d2b < best_d) { best_d = d2b; best_k = k + 1; }
    }
#undef DOT4

    // ---- outputs ----
    z_out[row] = (float)best_k;
    s_idx[tid] = best_k;
    __syncthreads();

    // cooperative q gather: bit-exact codebook rows, coalesced float4 stores
    const int lane16 = tid & 15;
    const int rsub   = tid >> 4;
    const float4* cb4 = (const float4*)cb;
    float4* q4 = (float4*)q_out;
    const int row_base = blockIdx.x * BLOCK;
#pragma unroll
    for (int it = 0; it < 16; ++it) {
        const int rl  = it * 16 + rsub;
        const int idx = s_idx[rl];
        q4[(size_t)(row_base + rl) * 16 + lane16] = cb4[idx * 16 + lane16];
    }
}

extern "C" void kernel_launch(void* const* d_in, const int* in_sizes, int n_in,
                              void* d_out, int out_size, void* d_ws, size_t ws_size,
                              hipStream_t stream) {
    const float* h  = (const float*)d_in[0];
    const float* cb = (const float*)d_in[1];
    float* out = (float*)d_out;
    float* z_out = out;              // 131072 floats
    float* q_out = out + N_ROWS;     // 131072*64 floats

    vq_argmin_kernel<<<dim3(N_ROWS / BLOCK), dim3(BLOCK), 0, stream>>>(h, cb, z_out, q_out);
}

// Round 4
// 442.235 us; speedup vs baseline: 1.5287x; 1.2429x over previous
//
#include <hip/hip_runtime.h>

#define N_ROWS 131072
#define KCODES 1024
#define DIM 64
#define BLOCK 256

// h: [32, 64, 64, 64] fp32 (B, D, H, W) -> row n = b*4096 + y*64 + x reads h[b][d][y][x]
// codebook: [1024, 64] fp32
// out: [131072] z-as-float ++ [131072*64] q fp32

__global__ void
__attribute__((amdgpu_flat_work_group_size(256, 256), amdgpu_waves_per_eu(2, 2)))
vq_argmin_kernel(
    const float* __restrict__ h,
    const float* __restrict__ cb,
    float* __restrict__ z_out,
    float* __restrict__ q_out)
{
    __shared__ float s_c2[KCODES];
    __shared__ int   s_idx[BLOCK];

    const int tid = threadIdx.x;
    const int row = blockIdx.x * BLOCK + tid;

    // ---- c2[k] = ||codebook[k]||^2, numpy-pairwise order (8 strided accumulators) ----
    {
#pragma clang fp contract(off)
#pragma unroll
        for (int kk = 0; kk < KCODES / BLOCK; ++kk) {
            const int k = kk * BLOCK + tid;
            const float* c = cb + k * DIM;
            float r0 = c[0]*c[0], r1 = c[1]*c[1], r2 = c[2]*c[2], r3 = c[3]*c[3];
            float r4 = c[4]*c[4], r5 = c[5]*c[5], r6 = c[6]*c[6], r7 = c[7]*c[7];
#pragma unroll
            for (int i = 1; i < 8; ++i) {
                r0 = r0 + c[i*8+0]*c[i*8+0];
                r1 = r1 + c[i*8+1]*c[i*8+1];
                r2 = r2 + c[i*8+2]*c[i*8+2];
                r3 = r3 + c[i*8+3]*c[i*8+3];
                r4 = r4 + c[i*8+4]*c[i*8+4];
                r5 = r5 + c[i*8+5]*c[i*8+5];
                r6 = r6 + c[i*8+6]*c[i*8+6];
                r7 = r7 + c[i*8+7]*c[i*8+7];
            }
            s_c2[k] = ((r0 + r1) + (r2 + r3)) + ((r4 + r5) + (r6 + r7));
        }
    }
    __syncthreads();

    // ---- this thread's row: 16 float4 pinned via asm ----
    const int b  = row >> 12;
    const int yx = row & 4095;
    const float* hp = h + (size_t)b * (DIM * 4096) + yx;

#define LD(d) hp[(size_t)(d) * 4096]
#define XDECL(n) float4 x##n = make_float4(LD(4*(n)+0), LD(4*(n)+1), LD(4*(n)+2), LD(4*(n)+3)); \
    asm("" : "+v"(x##n.x), "+v"(x##n.y), "+v"(x##n.z), "+v"(x##n.w));
    XDECL(0)  XDECL(1)  XDECL(2)  XDECL(3)
    XDECL(4)  XDECL(5)  XDECL(6)  XDECL(7)
    XDECL(8)  XDECL(9)  XDECL(10) XDECL(11)
    XDECL(12) XDECL(13) XDECL(14) XDECL(15)
#undef XDECL
#undef LD

    // ---- S = ||x||^2, numpy pairwise (8 accumulators over elems i*8+j) ----
    float S;
    {
#pragma clang fp contract(off)
        float r0 = x0.x*x0.x, r1 = x0.y*x0.y, r2 = x0.z*x0.z, r3 = x0.w*x0.w;
        float r4 = x1.x*x1.x, r5 = x1.y*x1.y, r6 = x1.z*x1.z, r7 = x1.w*x1.w;
#define SQACC(ve, vo) \
        r0 = r0 + ve.x*ve.x; r1 = r1 + ve.y*ve.y; r2 = r2 + ve.z*ve.z; r3 = r3 + ve.w*ve.w; \
        r4 = r4 + vo.x*vo.x; r5 = r5 + vo.y*vo.y; r6 = r6 + vo.z*vo.z; r7 = r7 + vo.w*vo.w;
        SQACC(x2,  x3)  SQACC(x4,  x5)  SQACC(x6,  x7)
        SQACC(x8,  x9)  SQACC(x10, x11) SQACC(x12, x13)
        SQACC(x14, x15)
#undef SQACC
        S = ((r0 + r1) + (r2 + r3)) + ((r4 + r5) + (r6 + r7));
    }

    // ---- main loop: 2 codes/iter, 2 independent sequential FMA chains ----
    float best_d = 3.4e38f;
    int   best_k = 0;

#define DOT4(v, base) \
        a0 = __builtin_fmaf(v.x, c0[(base)+0], a0); a1 = __builtin_fmaf(v.x, c1[(base)+0], a1); \
        a0 = __builtin_fmaf(v.y, c0[(base)+1], a0); a1 = __builtin_fmaf(v.y, c1[(base)+1], a1); \
        a0 = __builtin_fmaf(v.z, c0[(base)+2], a0); a1 = __builtin_fmaf(v.z, c1[(base)+2], a1); \
        a0 = __builtin_fmaf(v.w, c0[(base)+3], a0); a1 = __builtin_fmaf(v.w, c1[(base)+3], a1);

    for (int k = 0; k < KCODES; k += 2) {
        const float* c0 = cb + (k << 6);   // wave-uniform -> s_load stream
        const float* c1 = c0 + DIM;
        float a0 = 0.0f, a1 = 0.0f;
        DOT4(x0,  0)  DOT4(x1,  4)  DOT4(x2,  8)  DOT4(x3,  12)
        DOT4(x4,  16) DOT4(x5,  20) DOT4(x6,  24) DOT4(x7,  28)
        DOT4(x8,  32) DOT4(x9,  36) DOT4(x10, 40) DOT4(x11, 44)
        DOT4(x12, 48) DOT4(x13, 52) DOT4(x14, 56) DOT4(x15, 60)

        float d2a, d2b;
        {
#pragma clang fp contract(off)
            float ta = 2.0f * a0;     // exact
            float tb = 2.0f * a1;
            float ua = S - ta;        // rounded like np
            float ub = S - tb;
            d2a = ua + s_c2[k];
            d2b = ub + s_c2[k + 1];
        }
        if (d2a < best_d) { best_d = d2a; best_k = k; }
        if (d2b < best_d) { best_d = d2b; best_k = k + 1; }
    }
#undef DOT4

    // ---- outputs ----
    z_out[row] = (float)best_k;
    s_idx[tid] = best_k;
    __syncthreads();

    // cooperative q gather: bit-exact codebook rows, coalesced float4 stores
    const int lane16 = tid & 15;
    const int rsub   = tid >> 4;
    const float4* cb4 = (const float4*)cb;
    float4* q4 = (float4*)q_out;
    const int row_base = blockIdx.x * BLOCK;
#pragma unroll
    for (int it = 0; it < 16; ++it) {
        const int rl  = it * 16 + rsub;
        const int idx = s_idx[rl];
        q4[(size_t)(row_base + rl) * 16 + lane16] = cb4[idx * 16 + lane16];
    }
}

extern "C" void kernel_launch(void* const* d_in, const int* in_sizes, int n_in,
                              void* d_out, int out_size, void* d_ws, size_t ws_size,
                              hipStream_t stream) {
    const float* h  = (const float*)d_in[0];
    const float* cb = (const float*)d_in[1];
    float* out = (float*)d_out;
    float* z_out = out;              // 131072 floats
    float* q_out = out + N_ROWS;     // 131072*64 floats

    vq_argmin_kernel<<<dim3(N_ROWS / BLOCK), dim3(BLOCK), 0, stream>>>(h, cb, z_out, q_out);
}